// Round 12
// baseline (311.040 us; speedup 1.0000x reference)
//
#include <hip/hip_runtime.h>
#include <hip/hip_bf16.h>

#define MM 127
#define CHUNK_U16 4096        // per (matrix, k-chunk): 512 slots * 8 u16 = 8 KB
#define MAT_U16   16384       // 4 chunks per matrix = 32 KB
#define ARR_U16   1048576     // 64 matrices = 2 MB per array (X, Y)
#define QS_STRIDE 136         // per-lane stream stride (dwords); 136%32=8 -> uniform banks
#define QS_DWORDS (64 * QS_STRIDE)   // 8704 dwords = 34,816 B
#define NPAIRS 8256

typedef __attribute__((ext_vector_type(8))) short short8;
typedef __attribute__((ext_vector_type(4))) float floatx4;
typedef __attribute__((ext_vector_type(4))) unsigned int uint4v;

__device__ __forceinline__ unsigned int pack_bf16_rne(float a, float b) {
  float2 rr; rr.x = a; rr.y = b;
  __hip_bfloat162 hp = __float22bfloat162_rn(rr);
  unsigned int hu; __builtin_memcpy(&hu, &hp, 4);
  return hu;
}

__device__ __forceinline__ void gload_lds16(const void* g, void* l) {
  __builtin_amdgcn_global_load_lds(
      (const __attribute__((address_space(1))) unsigned int*)g,
      (__attribute__((address_space(3))) unsigned int*)l, 16, 0, 0);
}

// wave_shr:1 via DPP: lane l gets lane l-1's value; lane 0 gets 0 (bound_ctrl)
__device__ __forceinline__ float wave_shr1(float x) {
  return __int_as_float(__builtin_amdgcn_update_dpp(
      0, __float_as_int(x), 0x138, 0xf, 0xf, true));
}

// ---- forced-pipeline PDE load/wait primitives (R5/R9/R10: proven) ----
// DS_LOAD: inline-asm ds_read_b128 -- volatile, so issue ORDER is pinned.
// WAITK: s_waitcnt lgkmcnt(N) with the consumed bank as a tied "+v" operand:
// hard SSA dep -> consuming VALU cannot hoist above the wait (rule #18).
#define DS_LOAD(dst, g_) do {                                         \
    int pb_ = 4 * (g_) - shift;                                       \
    pb_ = pb_ < 0 ? 132 : (pb_ > 128 ? 128 : pb_);                    \
    unsigned a_ = (lbase + (unsigned)pb_) * 4u;                       \
    asm volatile("ds_read_b128 %0, %1" : "=&v"(dst) : "v"(a_));       \
  } while (0)
#define WAITK(n_, b_) asm volatile("s_waitcnt lgkmcnt(" #n_ ")" : "+v"(b_))

// ---- prep: increments -> RNE bf16, stored as the LDS frag image ----
// Swizzle: slot (r, h) holds 8-elem group g = h ^ ((r>>1)&3).  Reader lane
// (quad q, row r) reads slot h = q ^ ((r>>1)&3) -> bank-quad
// (4r + h) mod 8 covers all 8 quads exactly 2x per 16-lane phase (2-way = free).
__global__ __launch_bounds__(256) void prep_kernel(
    const float* __restrict__ X, const float* __restrict__ Y,
    unsigned short* __restrict__ base, float* __restrict__ acc,
    unsigned int* __restrict__ cnt)
{
  if (blockIdx.x == 0 && threadIdx.x == 0) { acc[0] = 0.f; cnt[0] = 0u; }
  const int bid = blockIdx.x;
  const int c = bid & 3;
  const int m = (bid >> 2) & 63;
  const int isY = bid >> 8;
  const float* src = (isY ? Y : X) + m * 128 * 128;
  unsigned short* dst = base + isY * ARR_U16 + m * MAT_U16 + c * CHUNK_U16;

  for (int s = threadIdx.x; s < 512; s += 256) {
    const int r = s >> 2;
    const int g = (s & 3) ^ ((r >> 1) & 3);
    uint4 hv = make_uint4(0, 0, 0, 0);
    if (r < MM) {
      const float* p = src + r * 128 + c * 32 + g * 8;
      float4 u0 = *reinterpret_cast<const float4*>(p);
      float4 u1 = *reinterpret_cast<const float4*>(p + 4);
      float4 v0 = *reinterpret_cast<const float4*>(p + 128);
      float4 v1 = *reinterpret_cast<const float4*>(p + 132);
      hv.x = pack_bf16_rne(v0.x - u0.x, v0.y - u0.y);
      hv.y = pack_bf16_rne(v0.z - u0.z, v0.w - u0.w);
      hv.z = pack_bf16_rne(v1.x - u1.x, v1.y - u1.y);
      hv.w = pack_bf16_rne(v1.z - u1.z, v1.w - u1.w);
    }
    *reinterpret_cast<uint4*>(dst + s * 8) = hv;
  }
}

__global__ __launch_bounds__(256, 4) void sig_pair_kernel(
    const unsigned short* __restrict__ base, float* __restrict__ acc,
    unsigned int* __restrict__ cnt, unsigned int* __restrict__ out)
{
  // LDS 34,816 B (4 blocks/CU).
  // GEMM phase: double-buffered staging, buf c&1 @ (c&1)*8192 u16 (A@+0, B@+4096).
  // PDE phase: lane-skewed stream qS[64][136] dwords aliases everything:
  //   qS[l][phys] = packed bf16 (mE low, mO high) consumed by lane l at iter t,
  //   phys = t - 4*(l>>1) - 4*(l&1) + 4.  Unwritten slots = 0 -> m-1 = -1 border.
  //   phys 132..135 = dedicated zero pad for pre-band clamped reads.
  // R12: finalize merged via last-arrival pattern (saves one dispatch).
  __shared__ unsigned int smw[QS_DWORDS];
  unsigned short* const sm = reinterpret_cast<unsigned short*>(smw);
  const int tid = threadIdx.x;
  const int bid = blockIdx.x;

  // ---- R10 stagger (banked; ~1 us, harmless) ----
  if (bid < 1024) {
    const int q = (bid >> 8) & 3;
    for (int i = 0; i < q; ++i) __builtin_amdgcn_s_sleep(127);
  }

  // ---- decode block -> (gram type, a, b, weight) ----
  float w;
  int a, b, srcA, srcB;
  if (bid < 4160) {
    int p = bid;
    srcA = 0;
    if (p >= 2080) { p -= 2080; srcA = 1; }
    srcB = srcA;
    int ia = (int)((sqrtf(8.0f * (float)p + 1.0f) - 1.0f) * 0.5f);
    while ((ia + 1) * (ia + 2) / 2 <= p) ia++;
    while (ia * (ia + 1) / 2 > p) ia--;
    int ib = p - ia * (ia + 1) / 2;
    a = ia; b = ib;
    w = (a == b ? 1.0f : 2.0f) / 4096.0f;
  } else {
    int p = bid - 4160;
    a = p >> 6; b = p & 63;
    srcA = 0; srcB = 1;
    w = -2.0f / 4096.0f;
  }
  const unsigned short* Am = base + srcA * ARR_U16 + a * MAT_U16;
  const unsigned short* Bm = base + srcB * ARR_U16 + b * MAT_U16;

  const int wid = tid >> 6, lane = tid & 63;
  const int row0 = (wid >> 1) * 64, col0 = (wid & 1) * 64;
  const int lrow = lane & 15, quad = lane >> 4;

  // this wave's DMA quarter: waves 0,1 -> A halves; waves 2,3 -> B halves
  const unsigned short* gp = ((wid < 2) ? Am : Bm) + (wid & 1) * 2048 + lane * 8;
  const unsigned int dq = wid * 2048;   // u16 offset inside a staging buf

  floatx4 acc4[4][4];
#pragma unroll
  for (int tr = 0; tr < 4; ++tr)
#pragma unroll
    for (int tc = 0; tc < 4; ++tc) acc4[tr][tc] = (floatx4){0.f, 0.f, 0.f, 0.f};

  // preload chunk 0 into buf 0
#pragma unroll
  for (int s = 0; s < 4; ++s)
    gload_lds16(gp + s * 512, &sm[dq + s * 512]);

  for (int c = 0; c < 4; ++c) {
    __syncthreads();   // drains DMA (compiler: vmcnt(0) before barrier)
    if (c < 3) {       // prefetch next chunk into the other buffer
      const unsigned short* g = gp + (c + 1) * CHUNK_U16;
      const unsigned int db_ = ((c + 1) & 1) * 8192 + dq;
#pragma unroll
      for (int s = 0; s < 4; ++s)
        gload_lds16(g + s * 512, &sm[db_ + s * 512]);
    }
    const unsigned int bb = (c & 1) * 8192;
    short8 bh[4];
#pragma unroll
    for (int tc = 0; tc < 4; ++tc) {
      int r = col0 + tc * 16 + lrow;
      int off = r * 32 + ((quad ^ ((r >> 1) & 3)) * 8);
      bh[tc] = *reinterpret_cast<const short8*>(&sm[bb + 4096 + off]);
    }
#pragma unroll
    for (int tr = 0; tr < 4; ++tr) {
      int r = row0 + tr * 16 + lrow;
      int off = r * 32 + ((quad ^ ((r >> 1) & 3)) * 8);
      short8 ah = *reinterpret_cast<const short8*>(&sm[bb + off]);
#pragma unroll
      for (int tc = 0; tc < 4; ++tc)
        acc4[tr][tc] = __builtin_amdgcn_mfma_f32_16x16x32_bf16(ah, bh[tc], acc4[tr][tc], 0, 0, 0);
    }
  }
  __syncthreads();   // all staging reads done; alias qS over the buffer

  // ---- zero-fill the stream image (zeros = m-1 == -1 borders), b128 ----
  {
    uint4 z = make_uint4(0u, 0u, 0u, 0u);
    uint4* smw4 = reinterpret_cast<uint4*>(smw);
    for (int i = tid; i < QS_DWORDS / 4; i += 256) smw4[i] = z;
  }
  __syncthreads();

  // ---- epilogue: write M (bf16) directly into consumer (lane, slot) ----
  // odd jm -> E (low u16) of lane (jm+1)/2; even jm -> O (high u16) of lane jm/2.
  // phys = im + jm + 5 - 4*(lt>>1) - 4*(lt&1)
  // im0 = row0+tr*16+quad*4 <= 124, so e=0..2 always valid; e=3 iff im0 != 124.
#pragma unroll
  for (int tr = 0; tr < 4; ++tr) {
    const int im0 = row0 + tr * 16 + quad * 4;
#pragma unroll
    for (int tc = 0; tc < 4; ++tc) {
      const int jm = col0 + tc * 16 + lrow;
      if (jm < MM) {
        const int lt = (jm + 1) >> 1;
        const int half = (jm & 1) ? 0 : 1;
        const int phys0 = im0 + jm + 5 - 4 * (lt >> 1) - 4 * (lt & 1);
        unsigned short* p = &sm[(lt * QS_STRIDE + phys0) * 2 + half];
        unsigned int u01 = pack_bf16_rne(acc4[tr][tc][0], acc4[tr][tc][1]);
        unsigned int u23 = pack_bf16_rne(acc4[tr][tc][2], acc4[tr][tc][3]);
        p[0] = (unsigned short)u01;
        p[2] = (unsigned short)(u01 >> 16);
        p[4] = (unsigned short)u23;
        if (im0 + 3 < MM) p[6] = (unsigned short)(u23 >> 16);
      }
    }
  }
  __syncthreads();

  // ---- Phase 2: streamed PDE, DPP cross-lane, FORCED depth-8 pipeline ----
  // Ring of 8 named uint4 banks, loads via volatile asm ds_read_b128 (issue
  // order pinned), consumption gated by asm s_waitcnt lgkmcnt(N) with the
  // bank as tied "+v" operand.  Ledger: preload g=0..7; main loop g=0..55
  // waits lgkmcnt(7) and reissues g+8 (last = 63); tail waits 7..0.  DS
  // returns are in-order per wave, so counted lgkmcnt is exact.
  // Steps: 56*4 + 7*4 + 2 = 254 = 2*MM.
  if (wid == ((bid >> 8) & 3)) {
    const int l = lane;
    const int shift = 4 * (l >> 1) + 4 * (l & 1) - 4;
    const unsigned int lbase = l * QS_STRIDE;

    float curE = 1.f, curO = 1.f;
    float npE = (l == 0) ? 0.f : 1.f, npO = 1.f;

    auto estep = [&](unsigned int u) {
      float mE = __uint_as_float(u << 16) - 1.0f;
      float mO = __uint_as_float(u & 0xFFFF0000u) - 1.0f;
      float ncE = wave_shr1(curO);
      float ncO = curE;
      float vE = (curE + npE * mE) + ncE;
      float vO = (curO + npO * mO) + ncO;
      npE = ncE; npO = ncO;
      curE = vE; curO = vO;
    };
    auto do4 = [&](uint4v cur) {
      estep(cur[0]); estep(cur[1]); estep(cur[2]); estep(cur[3]);
    };

    uint4v B0, B1, B2, B3, B4, B5, B6, B7;
    DS_LOAD(B0, 0); DS_LOAD(B1, 1); DS_LOAD(B2, 2); DS_LOAD(B3, 3);
    DS_LOAD(B4, 4); DS_LOAD(B5, 5); DS_LOAD(B6, 6); DS_LOAD(B7, 7);

    for (int k = 0; k < 7; ++k) {          // g = 8k .. 8k+7
      const int gb = 8 * k + 8;
      WAITK(7, B0); do4(B0); DS_LOAD(B0, gb + 0);
      WAITK(7, B1); do4(B1); DS_LOAD(B1, gb + 1);
      WAITK(7, B2); do4(B2); DS_LOAD(B2, gb + 2);
      WAITK(7, B3); do4(B3); DS_LOAD(B3, gb + 3);
      WAITK(7, B4); do4(B4); DS_LOAD(B4, gb + 4);
      WAITK(7, B5); do4(B5); DS_LOAD(B5, gb + 5);
      WAITK(7, B6); do4(B6); DS_LOAD(B6, gb + 6);
      WAITK(7, B7); do4(B7); DS_LOAD(B7, gb + 7);
    }
    // tail: g = 56..62 full groups, then t = 252, 253 from g = 63
    WAITK(7, B0); do4(B0);
    WAITK(6, B1); do4(B1);
    WAITK(5, B2); do4(B2);
    WAITK(4, B3); do4(B3);
    WAITK(3, B4); do4(B4);
    WAITK(2, B5); do4(B5);
    WAITK(1, B6); do4(B6);
    WAITK(0, B7); estep(B7[0]); estep(B7[1]);

    if (l == 63) {
      atomicAdd(acc, w * curO);            // col 127 = odd col of lane 63
      // ---- merged finalize: last arrival converts and writes output ----
      __threadfence();                     // release my acc add
      unsigned int old = atomicAdd(cnt, 1u);
      if (old == NPAIRS - 1) {
        __threadfence();                   // acquire all acc adds
        float v = atomicAdd(acc, 0.0f);    // atomic read: L2-coherent final sum
        __hip_bfloat16 bv = __float2bfloat16(v);
        unsigned short u;
        __builtin_memcpy(&u, &bv, sizeof(u));
        out[0] = ((unsigned int)u << 16) | (unsigned int)u;
      }
    }
  }
}

extern "C" void kernel_launch(void* const* d_in, const int* in_sizes, int n_in,
                              void* d_out, int out_size, void* d_ws, size_t ws_size,
                              hipStream_t stream) {
  const float* X = (const float*)d_in[0];
  const float* Y = (const float*)d_in[1];
  float* acc = (float*)d_ws;                                     // 4 B @ 0
  unsigned int* cnt = (unsigned int*)((char*)d_ws + 8);          // 4 B @ 8
  unsigned short* base = (unsigned short*)((char*)d_ws + 1024);  // 4 MB arrays

  prep_kernel<<<512, 256, 0, stream>>>(X, Y, base, acc, cnt);
  sig_pair_kernel<<<8256, 256, 0, stream>>>(base, acc, cnt, (unsigned int*)d_out);
}

// Round 13
// 181.066 us; speedup vs baseline: 1.7178x; 1.7178x over previous
//
#include <hip/hip_runtime.h>
#include <hip/hip_bf16.h>

#define MM 127
#define CHUNK_U16 4096        // per (matrix, k-chunk): 512 slots * 8 u16 = 8 KB
#define MAT_U16   16384       // 4 chunks per matrix = 32 KB
#define ARR_U16   1048576     // 64 matrices = 2 MB per array (X, Y)
#define QS_STRIDE 136         // per-lane stream stride (dwords); 136%32=8 -> uniform banks
#define QS_DWORDS (64 * QS_STRIDE)   // 8704 dwords = 34,816 B

typedef __attribute__((ext_vector_type(8))) short short8;
typedef __attribute__((ext_vector_type(4))) float floatx4;
typedef __attribute__((ext_vector_type(4))) unsigned int uint4v;

__device__ __forceinline__ unsigned int pack_bf16_rne(float a, float b) {
  float2 rr; rr.x = a; rr.y = b;
  __hip_bfloat162 hp = __float22bfloat162_rn(rr);
  unsigned int hu; __builtin_memcpy(&hu, &hp, 4);
  return hu;
}

__device__ __forceinline__ void gload_lds16(const void* g, void* l) {
  __builtin_amdgcn_global_load_lds(
      (const __attribute__((address_space(1))) unsigned int*)g,
      (__attribute__((address_space(3))) unsigned int*)l, 16, 0, 0);
}

// wave_shr:1 via DPP: lane l gets lane l-1's value; lane 0 gets 0 (bound_ctrl)
__device__ __forceinline__ float wave_shr1(float x) {
  return __int_as_float(__builtin_amdgcn_update_dpp(
      0, __float_as_int(x), 0x138, 0xf, 0xf, true));
}

// ---- forced-pipeline PDE load/wait primitives (R5/R9: proven, kept) ----
// DS_LOAD: inline-asm ds_read_b128 -- volatile, so issue ORDER is pinned.
// WAITK: s_waitcnt lgkmcnt(N) with the consumed bank as a tied "+v" operand:
// hard SSA dep -> consuming VALU cannot hoist above the wait (rule #18).
#define DS_LOAD(dst, g_) do {                                         \
    int pb_ = 4 * (g_) - shift;                                       \
    pb_ = pb_ < 0 ? 132 : (pb_ > 128 ? 128 : pb_);                    \
    unsigned a_ = (lbase + (unsigned)pb_) * 4u;                       \
    asm volatile("ds_read_b128 %0, %1" : "=&v"(dst) : "v"(a_));       \
  } while (0)
#define WAITK(n_, b_) asm volatile("s_waitcnt lgkmcnt(" #n_ ")" : "+v"(b_))

// ---- prep: increments -> RNE bf16, stored as the LDS frag image ----
// Swizzle: slot (r, h) holds 8-elem group g = h ^ ((r>>1)&3).  Reader lane
// (quad q, row r) reads slot h = q ^ ((r>>1)&3) -> bank-quad
// (4r + h) mod 8 covers all 8 quads exactly 2x per 16-lane phase (2-way = free).
__global__ __launch_bounds__(256) void prep_kernel(
    const float* __restrict__ X, const float* __restrict__ Y,
    unsigned short* __restrict__ base, float* __restrict__ acc)
{
  if (blockIdx.x == 0 && threadIdx.x == 0) acc[0] = 0.f;
  const int bid = blockIdx.x;
  const int c = bid & 3;
  const int m = (bid >> 2) & 63;
  const int isY = bid >> 8;
  const float* src = (isY ? Y : X) + m * 128 * 128;
  unsigned short* dst = base + isY * ARR_U16 + m * MAT_U16 + c * CHUNK_U16;

  for (int s = threadIdx.x; s < 512; s += 256) {
    const int r = s >> 2;
    const int g = (s & 3) ^ ((r >> 1) & 3);
    uint4 hv = make_uint4(0, 0, 0, 0);
    if (r < MM) {
      const float* p = src + r * 128 + c * 32 + g * 8;
      float4 u0 = *reinterpret_cast<const float4*>(p);
      float4 u1 = *reinterpret_cast<const float4*>(p + 4);
      float4 v0 = *reinterpret_cast<const float4*>(p + 128);
      float4 v1 = *reinterpret_cast<const float4*>(p + 132);
      hv.x = pack_bf16_rne(v0.x - u0.x, v0.y - u0.y);
      hv.y = pack_bf16_rne(v0.z - u0.z, v0.w - u0.w);
      hv.z = pack_bf16_rne(v1.x - u1.x, v1.y - u1.y);
      hv.w = pack_bf16_rne(v1.z - u1.z, v1.w - u1.w);
    }
    *reinterpret_cast<uint4*>(dst + s * 8) = hv;
  }
}

__global__ __launch_bounds__(256, 4) void sig_pair_kernel(
    const unsigned short* __restrict__ base, float* __restrict__ acc)
{
  // LDS 34,816 B (4 blocks/CU).
  // GEMM phase: double-buffered staging, buf c&1 @ (c&1)*8192 u16 (A@+0, B@+4096).
  // PDE phase: lane-skewed stream qS[64][136] dwords aliases everything:
  //   qS[l][phys] = packed bf16 (mE low, mO high) consumed by lane l at iter t,
  //   phys = t - 4*(l>>1) - 4*(l&1) + 4.  Unwritten slots = 0 -> m-1 = -1 border.
  //   phys 132..135 = dedicated zero pad for pre-band clamped reads.
  __shared__ unsigned int smw[QS_DWORDS];
  unsigned short* const sm = reinterpret_cast<unsigned short*>(smw);
  const int tid = threadIdx.x;
  const int bid = blockIdx.x;

  // ---- R10: phase-stagger of the 4 resident blocks/CU ----
  // De-phase generation 0 by quarter-lifetime quanta (s_sleep(127) ~ 8128 cyc
  // ~ 3.4 us); co-resident gen-0 bids {c, c+256, c+512, c+768} get distinct
  // delays.  Measured: ~1.5 us better than without; occupancy signature
  // unchanged (stagger decays), kept as banked small win.
  if (bid < 1024) {
    const int q = (bid >> 8) & 3;
    for (int i = 0; i < q; ++i) __builtin_amdgcn_s_sleep(127);
  }

  // ---- decode block -> (gram type, a, b, weight) ----
  float w;
  int a, b, srcA, srcB;
  if (bid < 4160) {
    int p = bid;
    srcA = 0;
    if (p >= 2080) { p -= 2080; srcA = 1; }
    srcB = srcA;
    int ia = (int)((sqrtf(8.0f * (float)p + 1.0f) - 1.0f) * 0.5f);
    while ((ia + 1) * (ia + 2) / 2 <= p) ia++;
    while (ia * (ia + 1) / 2 > p) ia--;
    int ib = p - ia * (ia + 1) / 2;
    a = ia; b = ib;
    w = (a == b ? 1.0f : 2.0f) / 4096.0f;
  } else {
    int p = bid - 4160;
    a = p >> 6; b = p & 63;
    srcA = 0; srcB = 1;
    w = -2.0f / 4096.0f;
  }
  const unsigned short* Am = base + srcA * ARR_U16 + a * MAT_U16;
  const unsigned short* Bm = base + srcB * ARR_U16 + b * MAT_U16;

  const int wid = tid >> 6, lane = tid & 63;
  const int row0 = (wid >> 1) * 64, col0 = (wid & 1) * 64;
  const int lrow = lane & 15, quad = lane >> 4;

  // this wave's DMA quarter: waves 0,1 -> A halves; waves 2,3 -> B halves
  const unsigned short* gp = ((wid < 2) ? Am : Bm) + (wid & 1) * 2048 + lane * 8;
  const unsigned int dq = wid * 2048;   // u16 offset inside a staging buf

  floatx4 acc4[4][4];
#pragma unroll
  for (int tr = 0; tr < 4; ++tr)
#pragma unroll
    for (int tc = 0; tc < 4; ++tc) acc4[tr][tc] = (floatx4){0.f, 0.f, 0.f, 0.f};

  // preload chunk 0 into buf 0
#pragma unroll
  for (int s = 0; s < 4; ++s)
    gload_lds16(gp + s * 512, &sm[dq + s * 512]);

  for (int c = 0; c < 4; ++c) {
    __syncthreads();   // drains DMA (compiler: vmcnt(0) before barrier)
    if (c < 3) {       // prefetch next chunk into the other buffer
      const unsigned short* g = gp + (c + 1) * CHUNK_U16;
      const unsigned int db_ = ((c + 1) & 1) * 8192 + dq;
#pragma unroll
      for (int s = 0; s < 4; ++s)
        gload_lds16(g + s * 512, &sm[db_ + s * 512]);
    }
    const unsigned int bb = (c & 1) * 8192;
    short8 bh[4];
#pragma unroll
    for (int tc = 0; tc < 4; ++tc) {
      int r = col0 + tc * 16 + lrow;
      int off = r * 32 + ((quad ^ ((r >> 1) & 3)) * 8);
      bh[tc] = *reinterpret_cast<const short8*>(&sm[bb + 4096 + off]);
    }
#pragma unroll
    for (int tr = 0; tr < 4; ++tr) {
      int r = row0 + tr * 16 + lrow;
      int off = r * 32 + ((quad ^ ((r >> 1) & 3)) * 8);
      short8 ah = *reinterpret_cast<const short8*>(&sm[bb + off]);
#pragma unroll
      for (int tc = 0; tc < 4; ++tc)
        acc4[tr][tc] = __builtin_amdgcn_mfma_f32_16x16x32_bf16(ah, bh[tc], acc4[tr][tc], 0, 0, 0);
    }
  }
  __syncthreads();   // all staging reads done; alias qS over the buffer

  // ---- zero-fill the stream image (zeros = m-1 == -1 borders), b128 ----
  {
    uint4 z = make_uint4(0u, 0u, 0u, 0u);
    uint4* smw4 = reinterpret_cast<uint4*>(smw);
    for (int i = tid; i < QS_DWORDS / 4; i += 256) smw4[i] = z;
  }
  __syncthreads();

  // ---- epilogue: write M (bf16) directly into consumer (lane, slot) ----
  // odd jm -> E (low u16) of lane (jm+1)/2; even jm -> O (high u16) of lane jm/2.
  // phys = im + jm + 5 - 4*(lt>>1) - 4*(lt&1)
  // im0 = row0+tr*16+quad*4 <= 124, so e=0..2 always valid; e=3 iff im0 != 124.
#pragma unroll
  for (int tr = 0; tr < 4; ++tr) {
    const int im0 = row0 + tr * 16 + quad * 4;
#pragma unroll
    for (int tc = 0; tc < 4; ++tc) {
      const int jm = col0 + tc * 16 + lrow;
      if (jm < MM) {
        const int lt = (jm + 1) >> 1;
        const int half = (jm & 1) ? 0 : 1;
        const int phys0 = im0 + jm + 5 - 4 * (lt >> 1) - 4 * (lt & 1);
        unsigned short* p = &sm[(lt * QS_STRIDE + phys0) * 2 + half];
        unsigned int u01 = pack_bf16_rne(acc4[tr][tc][0], acc4[tr][tc][1]);
        unsigned int u23 = pack_bf16_rne(acc4[tr][tc][2], acc4[tr][tc][3]);
        p[0] = (unsigned short)u01;
        p[2] = (unsigned short)(u01 >> 16);
        p[4] = (unsigned short)u23;
        if (im0 + 3 < MM) p[6] = (unsigned short)(u23 >> 16);
      }
    }
  }
  __syncthreads();

  // ---- Phase 2: streamed PDE, DPP cross-lane, FORCED depth-8 pipeline ----
  // Ring of 8 named uint4 banks, loads via volatile asm ds_read_b128 (issue
  // order pinned), consumption gated by asm s_waitcnt lgkmcnt(N) with the
  // bank as tied "+v" operand.  Ledger: preload g=0..7; main loop g=0..55
  // waits lgkmcnt(7) and reissues g+8 (last = 63); tail waits 7..0.  DS
  // returns are in-order per wave, so counted lgkmcnt is exact.
  // Steps: 56*4 + 7*4 + 2 = 254 = 2*MM.
  if (wid == ((bid >> 8) & 3)) {
    const int l = lane;
    const int shift = 4 * (l >> 1) + 4 * (l & 1) - 4;
    const unsigned int lbase = l * QS_STRIDE;

    float curE = 1.f, curO = 1.f;
    float npE = (l == 0) ? 0.f : 1.f, npO = 1.f;

    auto estep = [&](unsigned int u) {
      float mE = __uint_as_float(u << 16) - 1.0f;
      float mO = __uint_as_float(u & 0xFFFF0000u) - 1.0f;
      float ncE = wave_shr1(curO);
      float ncO = curE;
      float vE = (curE + npE * mE) + ncE;
      float vO = (curO + npO * mO) + ncO;
      npE = ncE; npO = ncO;
      curE = vE; curO = vO;
    };
    auto do4 = [&](uint4v cur) {
      estep(cur[0]); estep(cur[1]); estep(cur[2]); estep(cur[3]);
    };

    uint4v B0, B1, B2, B3, B4, B5, B6, B7;
    DS_LOAD(B0, 0); DS_LOAD(B1, 1); DS_LOAD(B2, 2); DS_LOAD(B3, 3);
    DS_LOAD(B4, 4); DS_LOAD(B5, 5); DS_LOAD(B6, 6); DS_LOAD(B7, 7);

    for (int k = 0; k < 7; ++k) {          // g = 8k .. 8k+7
      const int gb = 8 * k + 8;
      WAITK(7, B0); do4(B0); DS_LOAD(B0, gb + 0);
      WAITK(7, B1); do4(B1); DS_LOAD(B1, gb + 1);
      WAITK(7, B2); do4(B2); DS_LOAD(B2, gb + 2);
      WAITK(7, B3); do4(B3); DS_LOAD(B3, gb + 3);
      WAITK(7, B4); do4(B4); DS_LOAD(B4, gb + 4);
      WAITK(7, B5); do4(B5); DS_LOAD(B5, gb + 5);
      WAITK(7, B6); do4(B6); DS_LOAD(B6, gb + 6);
      WAITK(7, B7); do4(B7); DS_LOAD(B7, gb + 7);
    }
    // tail: g = 56..62 full groups, then t = 252, 253 from g = 63
    WAITK(7, B0); do4(B0);
    WAITK(6, B1); do4(B1);
    WAITK(5, B2); do4(B2);
    WAITK(4, B3); do4(B3);
    WAITK(3, B4); do4(B4);
    WAITK(2, B5); do4(B5);
    WAITK(1, B6); do4(B6);
    WAITK(0, B7); estep(B7[0]); estep(B7[1]);

    if (l == 63) atomicAdd(acc, w * curO);   // col 127 = odd col of lane 63
  }
}

__global__ void finalize_kernel(const float* __restrict__ acc,
                                unsigned int* __restrict__ out) {
  float v = acc[0];
  __hip_bfloat16 bv = __float2bfloat16(v);
  unsigned short u;
  __builtin_memcpy(&u, &bv, sizeof(u));
  out[0] = ((unsigned int)u << 16) | (unsigned int)u;
}

extern "C" void kernel_launch(void* const* d_in, const int* in_sizes, int n_in,
                              void* d_out, int out_size, void* d_ws, size_t ws_size,
                              hipStream_t stream) {
  const float* X = (const float*)d_in[0];
  const float* Y = (const float*)d_in[1];
  float* acc = (float*)d_ws;                                     // 4 B @ 0
  unsigned short* base = (unsigned short*)((char*)d_ws + 1024);  // 4 MB arrays

  prep_kernel<<<512, 256, 0, stream>>>(X, Y, base, acc);
  sig_pair_kernel<<<8256, 256, 0, stream>>>(base, acc);
  finalize_kernel<<<1, 1, 0, stream>>>(acc, (unsigned int*)d_out);
}